// Round 7
// baseline (499.862 us; speedup 1.0000x reference)
//
#include <hip/hip_runtime.h>
#include <math.h>

// RITS recurrent model, MFMA bf16, ONE barrier per step.
// 256 blocks x 512 threads (8 waves), block owns 16 batch rows.
// Wave w owns jh cols [16w,16w+16). MFMA 16x16x32 lane layout:
//   cidx=l&15 (A row / D col), gidx=l>>4 (k-group of 8); D: row=4*gidx+v, col=cidx.
// Folding (round 6): Whh2 = W_hh + W_ih_x@W_reg, bias += W_ih_x@b_reg;
//   gates = Whh2@h_d + W_ih_m@m + W_ih_x@e + b,  e = m*(x - x_h).
// NEW: every wave redundantly computes x_h (its own 8 MFMAs), forms e in
// D-layout, transposes via per-wave LDS scratch (no barrier needed: within-
// wave DS ops are ordered), then runs 4 e-MFMAs + pointwise. One barrier.
// Per-step schedule (par = t&1):
//   P: stg: d(t+1)->d_s[par^1], xm(t+1)->xm_s[(t+1)%3], issue loads t+2
//      all: h*gamma -> panel[par] h-section
//   bar1
//   Q: read aF0..3 (h), aM (m), ad (d); stg: m(t+1)->panel[par^1] m-section
//      8 xh MFMAs -> e (D-layout) -> escr (own wave) -> eF (A-layout)
//      20 gate/m MFMAs + 1 gamma MFMA + 4 e-MFMAs
//      wave0/1: imp store + loss acc (off-path)
//   R: pointwise (exp2/rcp, prescaled log2e), gamma exp2  [no barrier]
// Race audit (write -> barrier(s) -> read -> barrier -> rewrite):
//   h panel[par]:   W P(t) | bar1(t) | R Q(t) | bar1(t+1) | W P(t+2)  OK
//   m panel[par^1]: W Q(t) | bar1(t+1) | R Q(t+1) | bar1(t+2) | W Q(t+2) OK
//   d_s[par^1]:     W P(t) | bar1(t) | R Q(t) | bar1(t+1) | W P(t+2)  OK
//   xm_s[(t+1)%3]:  W P(t) | bar1(t+1) | R Q(t+1) | bar1(t+2) | W P(t+3) OK
//   escr[wv]:       same-wave only, DS-op order                        OK

#define T_LEN 252
#define FEAT  21
#define HID   128
#define BTOT  4096
#define BT    16
#define NB    (BTOT / BT)   // 256
#define NTHR  512
#define LOG2E 1.44269504088896f

// ws layout (floats)
#define WS_WHH2   0        // [512][128] folded recurrent weight
#define WS_RDEN   65536    // [256] (252 used)
#define WS_XL     65792    // [256]
#define WS_YNUM   66048    // [256]
#define WS_YDEN   66304    // [256]

typedef __attribute__((ext_vector_type(8))) short s16x8;
typedef __attribute__((ext_vector_type(4))) float f32x4;

#define MFMA16(A, B, C) __builtin_amdgcn_mfma_f32_16x16x32_bf16((A), (B), (C), 0, 0, 0)

__device__ __forceinline__ float exp2_f(float x) { return __builtin_amdgcn_exp2f(x); }
__device__ __forceinline__ float rcp_f(float x)  { return __builtin_amdgcn_rcpf(x); }
__device__ __forceinline__ unsigned short to_bf16(float x) {   // RNE (setup only)
    unsigned int u = __float_as_uint(x);
    return (unsigned short)((u + 0x7FFFu + ((u >> 16) & 1u)) >> 16);
}
__device__ __forceinline__ unsigned short to_bf16f(float x) {  // round-half-up, 2 ops
    return (unsigned short)((__float_as_uint(x) + 0x8000u) >> 16);
}

// ---- pre-pass 1: rden[t] = 1 / (sum_{b,f} masks[b][t][f] + 1e-5) ----
__global__ __launch_bounds__(1024) void rits_den(
    const float* __restrict__ masks, float* __restrict__ rden)
{
    const int t = blockIdx.x;
    const int tid = threadIdx.x;
    __shared__ float red[1024];
    float acc = 0.0f;
    if (tid < 48 * FEAT) {
        int r0 = tid / FEAT, f = tid - r0 * FEAT;
        for (int r = r0; r < BTOT; r += 48)
            acc += masks[r * (T_LEN * FEAT) + t * FEAT + f];
    }
    red[tid] = acc;
    __syncthreads();
    #pragma unroll
    for (int s = 512; s > 0; s >>= 1) {
        if (tid < s) red[tid] += red[tid + s];
        __syncthreads();
    }
    if (tid == 0) rden[t] = 1.0f / (red[0] + 1e-5f);
}

// ---- pre-pass 2: Whh2 = W_hh + W_ih[:, :FEAT] @ W_reg  (fp32) ----
__global__ __launch_bounds__(256) void rits_fold(
    const float* __restrict__ W_ih, const float* __restrict__ W_hh,
    const float* __restrict__ W_reg, float* __restrict__ whh2)
{
    int idx = blockIdx.x * 256 + threadIdx.x;       // 0..65535
    int j4 = idx >> 7, k = idx & (HID - 1);
    float acc = W_hh[j4 * HID + k];
    #pragma unroll
    for (int f = 0; f < FEAT; ++f)
        acc += W_ih[j4 * (2 * FEAT) + f] * W_reg[f * HID + k];
    whh2[idx] = acc;
}

__global__ __launch_bounds__(NTHR, 2) void rits_main(
    const float* __restrict__ values, const float* __restrict__ masks,
    const float* __restrict__ deltas,
    const float* __restrict__ labels, const float* __restrict__ is_train,
    const float* __restrict__ W_decay, const float* __restrict__ b_decay,
    const float* __restrict__ W_reg, const float* __restrict__ b_reg,
    const float* __restrict__ W_ih, const float* __restrict__ W_hh,
    const float* __restrict__ b_ih, const float* __restrict__ b_hh,
    const float* __restrict__ W_out, const float* __restrict__ b_out,
    const float* __restrict__ whh2, const float* __restrict__ rden,
    float* __restrict__ out_yh,     // [BTOT]
    float* __restrict__ out_imp,    // [BTOT][T][FEAT]
    float* __restrict__ xlpart, float* __restrict__ wsynum, float* __restrict__ wsyden)
{
    const int tid  = threadIdx.x;
    const int blk  = blockIdx.x;
    const int bbase = blk * BT;
    const int l    = tid & 63;
    const int wv   = tid >> 6;          // wave 0..7
    const int cidx = l & 15;
    const int gidx = l >> 4;            // k-group 0..3
    const int jh   = 16 * wv + cidx;    // owned hidden column

    // panel: k 0..127 h_d (bf16); k 128..159 m (f=k-128, f>=21 zero)
    __shared__ unsigned short ak_s[2][BT][200];
    __shared__ unsigned short d_s[2][BT][40];     // bf16 deltas, cols 21..39 zero
    __shared__ float2 xm_s[3][BT][22];            // (x, m) fp32, triple-buffered
    __shared__ unsigned short escr_s[8][BT][40];  // per-wave e scratch, f 0..31 (21+ =0)
    __shared__ float hfin_s[BT][HID + 4];
    __shared__ float rden_s[T_LEN];
    __shared__ float red_s[NTHR];

    for (int i = tid; i < 2 * BT * 200; i += NTHR) ((unsigned short*)ak_s)[i] = 0;
    for (int i = tid; i < 2 * BT * 40;  i += NTHR) ((unsigned short*)d_s)[i] = 0;
    for (int i = tid; i < 8 * BT * 40;  i += NTHR) ((unsigned short*)escr_s)[i] = 0;
    if (tid < T_LEN) rden_s[tid] = rden[tid];

    // ---------- one-time B-fragments (bf16), gate weights prescaled ----------
    // bfr_g[g][0..3]: Whh2 k 0..127 ; bfr_g[g][4]: W_ih_m (panel k 128..159)
    // bfr_e[g]: W_ih_x as B-frag for the e-MFMA (k == f, 0..31)
    s16x8 bfr_g[4][5], bfr_e[4];
    float bs_r[4];
    #pragma unroll
    for (int g = 0; g < 4; ++g) {
        const float sg = (g == 2) ? (2.0f * LOG2E) : LOG2E;
        const float* rh2 = whh2 + (g * HID + jh) * HID;
        const float* rih = W_ih + (g * HID + jh) * (2 * FEAT);
        #pragma unroll
        for (int s = 0; s < 4; ++s) {
            s16x8 fr;
            #pragma unroll
            for (int j = 0; j < 8; ++j)
                fr[j] = (short)to_bf16(rh2[32 * s + 8 * gidx + j] * sg);
            bfr_g[g][s] = fr;
        }
        {   // m-part: panel k 128..159 <-> f_m = k-128
            s16x8 fr;
            #pragma unroll
            for (int j = 0; j < 8; ++j) {
                int fm = 8 * gidx + j;
                fr[j] = (short)to_bf16(fm < FEAT ? rih[FEAT + fm] * sg : 0.0f);
            }
            bfr_g[g][4] = fr;
        }
        {   // e-part: k == f 0..31
            s16x8 fr;
            #pragma unroll
            for (int j = 0; j < 8; ++j) {
                int f = 8 * gidx + j;
                fr[j] = (short)to_bf16(f < FEAT ? rih[f] * sg : 0.0f);
            }
            bfr_e[g] = fr;
        }
        float bb = b_ih[g * HID + jh] + b_hh[g * HID + jh];
        #pragma unroll
        for (int f = 0; f < FEAT; ++f) bb += rih[f] * b_reg[f];   // fold b_reg
        bs_r[g] = bb * sg;
    }
    s16x8 bfr_d;
    {
        const float* rw = W_decay + jh * FEAT;
        #pragma unroll
        for (int j = 0; j < 8; ++j) {
            int f = 8 * gidx + j;
            bfr_d[j] = (short)to_bf16(f < FEAT ? rw[f] * LOG2E : 0.0f);
        }
    }
    const float bd_r = b_decay[jh] * LOG2E;
    // x_h B-frags, EVERY wave: tile A cols f=cidx (0..15), tile B cols f=16+cidx (<21)
    s16x8 bfr_xA[4], bfr_xB[4];
    const bool fBv = (cidx < FEAT - 16);            // cidx < 5
    #pragma unroll
    for (int s = 0; s < 4; ++s) {
        s16x8 fa, fb;
        #pragma unroll
        for (int j = 0; j < 8; ++j) {
            int k = 32 * s + 8 * gidx + j;
            fa[j] = (short)to_bf16(W_reg[cidx * HID + k]);
            fb[j] = (short)to_bf16(fBv ? W_reg[(16 + cidx) * HID + k] : 0.0f);
        }
        bfr_xA[s] = fa; bfr_xB[s] = fb;
    }
    const float brA = b_reg[cidx];
    const float brB = fBv ? b_reg[16 + cidx] : 0.0f;
    __syncthreads();   // zero-init visible before prologue panel writes

    // ---------- prologue: staging on waves 2..7 ----------
    const int st  = tid - 128;
    const bool stg = (st >= 0) && (st < BT * FEAT);
    const int rr = stg ? st / FEAT : 0;
    const int ff = stg ? (st - rr * FEAT) : 0;
    const int rowbase = (bbase + rr) * (T_LEN * FEAT) + ff;
    float nx = 0.f, nm = 0.f, nd = 0.f;
    if (stg) {
        float x0 = values[rowbase], m0 = masks[rowbase];
        xm_s[0][rr][ff] = make_float2(x0, m0);
        ak_s[0][rr][128 + ff] = to_bf16(m0);            // m(0) -> panel[0]
        nx = values[rowbase + FEAT];
        nm = masks[rowbase + FEAT];
        nd = deltas[rowbase + FEAT];
    }
    const int ibase = (bbase + 4 * gidx) * (T_LEN * FEAT);   // imp store base
    float c_r[4]   = {0.f, 0.f, 0.f, 0.f};
    float h_r[4]   = {0.f, 0.f, 0.f, 0.f};
    float gam_r[4] = {0.f, 0.f, 0.f, 0.f};   // h=0 at t=0 -> value irrelevant
    float xl_acc = 0.0f;
    __syncthreads();

    int bufw = 1;    // xm buffer written by P(t) = (t+1)%3
    int bufr = 0;    // xm buffer read by Q(t) = t%3
    for (int t = 0; t < T_LEN; ++t) {
        const int par = t & 1;

        // ---- P: flush t+1 stages, issue t+2 loads, h_d -> panel[par] ----
        float lx = 0.f, lm = 0.f, ld = 0.f;
        if (stg) {
            d_s[par ^ 1][rr][ff] = to_bf16f(nd);
            xm_s[bufw][rr][ff] = make_float2(nx, nm);
            int idx = (t + 2 < T_LEN) ? (t + 2) : (T_LEN - 1);
            int o = rowbase + idx * FEAT;
            lx = values[o]; lm = masks[o]; ld = deltas[o];
        }
        #pragma unroll
        for (int v = 0; v < 4; ++v)
            ak_s[par][4 * gidx + v][jh] = to_bf16f(h_r[v] * gam_r[v]);
        __syncthreads();                               // bar1 (the only barrier)

        // ---- Q ----
        s16x8 aF0 = *(const s16x8*)&ak_s[par][cidx][      8 * gidx];
        s16x8 aF1 = *(const s16x8*)&ak_s[par][cidx][ 32 + 8 * gidx];
        s16x8 aF2 = *(const s16x8*)&ak_s[par][cidx][ 64 + 8 * gidx];
        s16x8 aF3 = *(const s16x8*)&ak_s[par][cidx][ 96 + 8 * gidx];
        s16x8 aM  = *(const s16x8*)&ak_s[par][cidx][128 + 8 * gidx];
        s16x8 ad  = *(const s16x8*)&d_s[par ^ 1][cidx][8 * gidx];
        if (stg) ak_s[par ^ 1][rr][128 + ff] = to_bf16f(nm);   // m(t+1)

        // x_h (redundant per wave): 8 MFMAs
        f32x4 xaccA = {brA, brA, brA, brA};
        f32x4 xaccB = {brB, brB, brB, brB};
        xaccA = MFMA16(aF0, bfr_xA[0], xaccA); xaccB = MFMA16(aF0, bfr_xB[0], xaccB);
        xaccA = MFMA16(aF1, bfr_xA[1], xaccA); xaccB = MFMA16(aF1, bfr_xB[1], xaccB);
        xaccA = MFMA16(aF2, bfr_xA[2], xaccA); xaccB = MFMA16(aF2, bfr_xB[2], xaccB);
        xaccA = MFMA16(aF3, bfr_xA[3], xaccA); xaccB = MFMA16(aF3, bfr_xB[3], xaccB);

        // e in D-layout -> per-wave scratch (A-layout transpose via LDS)
        const float rd = rden_s[t];
        float eA[4], eB[4];
        #pragma unroll
        for (int v = 0; v < 4; ++v) {
            float2 xm = xm_s[bufr][4 * gidx + v][cidx];
            eA[v] = xm.y * (xm.x - xaccA[v]);
            escr_s[wv][4 * gidx + v][cidx] = to_bf16f(eA[v]);
            if (fBv) {
                float2 xb = xm_s[bufr][4 * gidx + v][16 + cidx];
                eB[v] = xb.y * (xb.x - xaccB[v]);
                escr_s[wv][4 * gidx + v][16 + cidx] = to_bf16f(eB[v]);
            }
        }

        // gate MFMAs (independent of e): hide the escr round-trip
        f32x4 acc0 = {bs_r[0], bs_r[0], bs_r[0], bs_r[0]};
        f32x4 acc1 = {bs_r[1], bs_r[1], bs_r[1], bs_r[1]};
        f32x4 acc2 = {bs_r[2], bs_r[2], bs_r[2], bs_r[2]};
        f32x4 acc3 = {bs_r[3], bs_r[3], bs_r[3], bs_r[3]};
        acc0 = MFMA16(aF0, bfr_g[0][0], acc0); acc1 = MFMA16(aF0, bfr_g[1][0], acc1);
        acc2 = MFMA16(aF0, bfr_g[2][0], acc2); acc3 = MFMA16(aF0, bfr_g[3][0], acc3);
        acc0 = MFMA16(aF1, bfr_g[0][1], acc0); acc1 = MFMA16(aF1, bfr_g[1][1], acc1);
        acc2 = MFMA16(aF1, bfr_g[2][1], acc2); acc3 = MFMA16(aF1, bfr_g[3][1], acc3);
        acc0 = MFMA16(aF2, bfr_g[0][2], acc0); acc1 = MFMA16(aF2, bfr_g[1][2], acc1);
        acc2 = MFMA16(aF2, bfr_g[2][2], acc2); acc3 = MFMA16(aF2, bfr_g[3][2], acc3);
        acc0 = MFMA16(aF3, bfr_g[0][3], acc0); acc1 = MFMA16(aF3, bfr_g[1][3], acc1);
        acc2 = MFMA16(aF3, bfr_g[2][3], acc2); acc3 = MFMA16(aF3, bfr_g[3][3], acc3);
        acc0 = MFMA16(aM, bfr_g[0][4], acc0);  acc1 = MFMA16(aM, bfr_g[1][4], acc1);
        acc2 = MFMA16(aM, bfr_g[2][4], acc2);  acc3 = MFMA16(aM, bfr_g[3][4], acc3);
        f32x4 gacc = {bd_r, bd_r, bd_r, bd_r};
        gacc = MFMA16(ad, bfr_d, gacc);

        // off-path: imputation store + loss (m is exactly 0/1 -> |e| = |x-xh|*m)
        if (wv == 0) {
            #pragma unroll
            for (int v = 0; v < 4; ++v) {
                out_imp[ibase + v * (T_LEN * FEAT) + t * FEAT + cidx] = xaccA[v] + eA[v];
                xl_acc += fabsf(eA[v]) * rd;
            }
        } else if (wv == 1 && fBv) {
            #pragma unroll
            for (int v = 0; v < 4; ++v) {
                out_imp[ibase + v * (T_LEN * FEAT) + t * FEAT + 16 + cidx] = xaccB[v] + eB[v];
                xl_acc += fabsf(eB[v]) * rd;
            }
        }

        // e A-fragment read (same-wave DS order) + 4 e-MFMAs
        s16x8 eF = *(const s16x8*)&escr_s[wv][cidx][8 * gidx];
        acc0 = MFMA16(eF, bfr_e[0], acc0);
        acc1 = MFMA16(eF, bfr_e[1], acc1);
        acc2 = MFMA16(eF, bfr_e[2], acc2);
        acc3 = MFMA16(eF, bfr_e[3], acc3);

        if (stg) { nx = lx; nm = lm; nd = ld; }

        // ---- R: pointwise (all regs) ----
        #pragma unroll
        for (int v = 0; v < 4; ++v) {
            float ig = rcp_f(1.0f + exp2_f(-acc0[v]));
            float fg = rcp_f(1.0f + exp2_f(-acc1[v]));
            float gg = 2.0f * rcp_f(1.0f + exp2_f(-acc2[v])) - 1.0f;
            float og = rcp_f(1.0f + exp2_f(-acc3[v]));
            c_r[v] = fg * c_r[v] + ig * gg;
            float th = 2.0f * rcp_f(1.0f + exp2_f(-2.0f * LOG2E * c_r[v])) - 1.0f;
            h_r[v] = og * th;
            gam_r[v] = exp2_f(-fmaxf(gacc[v], 0.0f));
        }
        int nb = bufw + 1; bufw = (nb > 2) ? 0 : nb;
        int nr = bufr + 1; bufr = (nr > 2) ? 0 : nr;
    }

    // ---------- epilogue ----------
    #pragma unroll
    for (int v = 0; v < 4; ++v) hfin_s[4 * gidx + v][jh] = h_r[v];
    red_s[tid] = xl_acc;
    __syncthreads();
    #pragma unroll
    for (int s = NTHR / 2; s > 0; s >>= 1) {
        if (tid < s) red_s[tid] += red_s[tid + s];
        __syncthreads();
    }
    if (tid == 0) xlpart[blk] = red_s[0];

    float yerr = 0.0f, ytr = 0.0f;
    if (tid < BT) {
        float acc = b_out[0];
        for (int k = 0; k < HID; ++k) acc += W_out[k] * hfin_s[tid][k];
        out_yh[bbase + tid] = acc;
        float it = is_train[bbase + tid];
        float dv = acc - labels[bbase + tid];
        yerr = dv * dv * it;
        ytr  = it;
    }
    #pragma unroll
    for (int s = 8; s > 0; s >>= 1) {
        yerr += __shfl_down(yerr, s);
        ytr  += __shfl_down(ytr, s);
    }
    if (tid == 0) { wsynum[blk] = yerr; wsyden[blk] = ytr; }
}

__global__ __launch_bounds__(256) void rits_final(
    const float* __restrict__ xlpart,
    const float* __restrict__ wsynum, const float* __restrict__ wsyden,
    float* __restrict__ d_out)
{
    __shared__ float sx[256], sy[256], sz[256];
    int tid = threadIdx.x;
    sx[tid] = xlpart[tid];
    sy[tid] = wsynum[tid];
    sz[tid] = wsyden[tid];
    __syncthreads();
    for (int s = 128; s > 0; s >>= 1) {
        if (tid < s) { sx[tid] += sx[tid + s]; sy[tid] += sy[tid + s]; sz[tid] += sz[tid + s]; }
        __syncthreads();
    }
    if (tid == 0) d_out[0] = sx[0] + sy[0] / (sz[0] + 1e-5f);
}

extern "C" void kernel_launch(void* const* d_in, const int* in_sizes, int n_in,
                              void* d_out, int out_size, void* d_ws, size_t ws_size,
                              hipStream_t stream)
{
    const float* values    = (const float*)d_in[0];
    const float* masks     = (const float*)d_in[1];
    const float* deltas    = (const float*)d_in[2];
    // d_in[3] evals, d_in[4] eval_masks : unused
    const float* labels    = (const float*)d_in[5];
    const float* is_train  = (const float*)d_in[6];
    const float* W_decay   = (const float*)d_in[7];
    const float* b_decay   = (const float*)d_in[8];
    const float* W_reg     = (const float*)d_in[9];
    const float* b_reg     = (const float*)d_in[10];
    const float* W_ih      = (const float*)d_in[11];
    const float* W_hh      = (const float*)d_in[12];
    const float* b_ih      = (const float*)d_in[13];
    const float* b_hh      = (const float*)d_in[14];
    const float* W_out     = (const float*)d_in[15];
    const float* b_out     = (const float*)d_in[16];

    float* ws     = (float*)d_ws;
    float* whh2   = ws + WS_WHH2;
    float* rden   = ws + WS_RDEN;
    float* xlpart = ws + WS_XL;
    float* wsynum = ws + WS_YNUM;
    float* wsyden = ws + WS_YDEN;

    float* out     = (float*)d_out;
    float* out_yh  = out + 1;
    float* out_imp = out + 1 + BTOT;

    rits_den<<<dim3(T_LEN), dim3(1024), 0, stream>>>(masks, rden);
    rits_fold<<<dim3(256), dim3(256), 0, stream>>>(W_ih, W_hh, W_reg, whh2);

    rits_main<<<dim3(NB), dim3(NTHR), 0, stream>>>(
        values, masks, deltas, labels, is_train,
        W_decay, b_decay, W_reg, b_reg, W_ih, W_hh, b_ih, b_hh, W_out, b_out,
        whh2, rden, out_yh, out_imp, xlpart, wsynum, wsyden);

    rits_final<<<dim3(1), dim3(256), 0, stream>>>(xlpart, wsynum, wsyden, out);
}

// Round 8
// 452.842 us; speedup vs baseline: 1.1038x; 1.1038x over previous
//
#include <hip/hip_runtime.h>
#include <math.h>

// RITS recurrent model, MFMA bf16, ONE barrier per step, register-resident e.
// 256 blocks x 512 threads (8 waves), block owns 16 batch rows.
// Wave w owns jh cols [16w,16w+16). MFMA 16x16x32 lane layout (m89-verified):
//   A-frag: lane(cidx=l&15, gidx=l>>4) elem j = A[row=cidx][k=8*gidx+j (+32s)]
//   B-frag: lane(cidx,gidx) elem j = B[k=8*gidx+j][col=cidx]
//   D     : lane(cidx,gidx) elem v = D[row=4*gidx+v][col=cidx]
//   => A-frag(M) == B-frag(M^T): reuse h_d A-frags as B for the swapped xh MFMA.
// Folding (round 6): Whh2 = W_hh + W_ih_x@W_reg, bias += W_ih_x@b_reg;
//   gates = Whh2@h_d + W_ih_m@m + W_ih_x@e + b,  e = m*(x - x_h).
// Swapped xh: xh^T = W_reg @ h_d^T : A = wregT frags (registers, loaded once),
//   B = aF0..3 (already loaded) -> lane holds xh[row=cidx][f=4*gidx+v] (2 tiles:
//   f and 16+f). e computed in VALU, packed into an e A-frag with the custom
//   (A/B-consistent) k-slot permutation f = j<4 ? 4*gidx+j : 16+4*gidx+(j-4).
//   bfr_e uses the same permutation. NO LDS transpose, NO second barrier.
// Per-step schedule (par = t&1):
//   P: stg: d(t+1)->d_s[par^1], xm(t+1)->xm_s[(t+1)%3], issue loads t+2
//      all: h*gamma -> panel[par] h-section
//   bar1 (only barrier)
//   Q: ds_reads (aF0-3, aM, ad, xm 8x); stg: m(t+1)->panel[par^1] m-section
//      8 swapped-xh MFMAs; 21 gate/m/gamma MFMAs (independent, hide xh);
//      e VALU -> eF; 4 e-MFMAs; waves 0,1: imp store + loss acc (off-path)
//   R: pointwise (exp2/rcp, prescaled log2e), gamma exp2  [no barrier]
// Race audit (write | bar | read | bar | rewrite):
//   h panel[par]:   W P(t) | bar1(t) | R Q(t) | bar1(t+1) | W P(t+2)   OK
//   m panel[par^1]: W Q(t) | bar1(t+1) | R Q(t+1) | bar1(t+2) | W Q(t+2) OK
//   d_s[par^1]:     W P(t) | bar1(t) | R Q(t) | bar1(t+1) | W P(t+2)   OK
//   xm_s[(t+1)%3]:  W P(t) | bar1(t+1) | R Q(t+1) | bar1(t+2) | W P(t+3) OK

#define T_LEN 252
#define FEAT  21
#define HID   128
#define BTOT  4096
#define BT    16
#define NB    (BTOT / BT)   // 256
#define NTHR  512
#define LOG2E 1.44269504088896f

// ws layout (floats)
#define WS_WHH2   0        // [512][128] folded recurrent weight
#define WS_RDEN   65536    // [256] (252 used)
#define WS_XL     65792    // [256]
#define WS_YNUM   66048    // [256]
#define WS_YDEN   66304    // [256]

typedef __attribute__((ext_vector_type(8))) short s16x8;
typedef __attribute__((ext_vector_type(4))) float f32x4;

#define MFMA16(A, B, C) __builtin_amdgcn_mfma_f32_16x16x32_bf16((A), (B), (C), 0, 0, 0)

__device__ __forceinline__ float exp2_f(float x) { return __builtin_amdgcn_exp2f(x); }
__device__ __forceinline__ float rcp_f(float x)  { return __builtin_amdgcn_rcpf(x); }
__device__ __forceinline__ unsigned short to_bf16(float x) {   // RNE (setup only)
    unsigned int u = __float_as_uint(x);
    return (unsigned short)((u + 0x7FFFu + ((u >> 16) & 1u)) >> 16);
}
__device__ __forceinline__ unsigned short to_bf16f(float x) {  // round-half-up, 2 ops
    return (unsigned short)((__float_as_uint(x) + 0x8000u) >> 16);
}

// ---- pre-pass 1: rden[t] = 1 / (sum_{b,f} masks[b][t][f] + 1e-5) ----
__global__ __launch_bounds__(1024) void rits_den(
    const float* __restrict__ masks, float* __restrict__ rden)
{
    const int t = blockIdx.x;
    const int tid = threadIdx.x;
    __shared__ float red[1024];
    float acc = 0.0f;
    if (tid < 48 * FEAT) {
        int r0 = tid / FEAT, f = tid - r0 * FEAT;
        for (int r = r0; r < BTOT; r += 48)
            acc += masks[r * (T_LEN * FEAT) + t * FEAT + f];
    }
    red[tid] = acc;
    __syncthreads();
    #pragma unroll
    for (int s = 512; s > 0; s >>= 1) {
        if (tid < s) red[tid] += red[tid + s];
        __syncthreads();
    }
    if (tid == 0) rden[t] = 1.0f / (red[0] + 1e-5f);
}

// ---- pre-pass 2: Whh2 = W_hh + W_ih[:, :FEAT] @ W_reg  (fp32) ----
__global__ __launch_bounds__(256) void rits_fold(
    const float* __restrict__ W_ih, const float* __restrict__ W_hh,
    const float* __restrict__ W_reg, float* __restrict__ whh2)
{
    int idx = blockIdx.x * 256 + threadIdx.x;       // 0..65535
    int j4 = idx >> 7, k = idx & (HID - 1);
    float acc = W_hh[j4 * HID + k];
    #pragma unroll
    for (int f = 0; f < FEAT; ++f)
        acc += W_ih[j4 * (2 * FEAT) + f] * W_reg[f * HID + k];
    whh2[idx] = acc;
}

__global__ __launch_bounds__(NTHR, 2) void rits_main(
    const float* __restrict__ values, const float* __restrict__ masks,
    const float* __restrict__ deltas,
    const float* __restrict__ labels, const float* __restrict__ is_train,
    const float* __restrict__ W_decay, const float* __restrict__ b_decay,
    const float* __restrict__ W_reg, const float* __restrict__ b_reg,
    const float* __restrict__ W_ih, const float* __restrict__ W_hh,
    const float* __restrict__ b_ih, const float* __restrict__ b_hh,
    const float* __restrict__ W_out, const float* __restrict__ b_out,
    const float* __restrict__ whh2, const float* __restrict__ rden,
    float* __restrict__ out_yh,     // [BTOT]
    float* __restrict__ out_imp,    // [BTOT][T][FEAT]
    float* __restrict__ xlpart, float* __restrict__ wsynum, float* __restrict__ wsyden)
{
    const int tid  = threadIdx.x;
    const int blk  = blockIdx.x;
    const int bbase = blk * BT;
    const int l    = tid & 63;
    const int wv   = tid >> 6;          // wave 0..7
    const int cidx = l & 15;
    const int gidx = l >> 4;            // k-group 0..3
    const int jh   = 16 * wv + cidx;    // owned hidden column

    // panel: k 0..127 h_d (bf16); k 128..159 m (f=k-128, f>=21 zero)
    __shared__ unsigned short ak_s[2][BT][200];
    __shared__ unsigned short d_s[2][BT][40];     // bf16 deltas, cols 21..39 zero
    __shared__ float2 xm_s[3][BT][33];            // (x,m) fp32, rows padded to 33
    __shared__ float hfin_s[BT][HID + 4];
    __shared__ float rden_s[T_LEN];
    __shared__ float red_s[NTHR];

    for (int i = tid; i < 2 * BT * 200; i += NTHR) ((unsigned short*)ak_s)[i] = 0;
    for (int i = tid; i < 2 * BT * 40;  i += NTHR) ((unsigned short*)d_s)[i] = 0;
    for (int i = tid; i < 3 * BT * 33;  i += NTHR) ((float2*)xm_s)[i] = make_float2(0.f, 0.f);
    if (tid < T_LEN) rden_s[tid] = rden[tid];

    // ---------- one-time B-fragments (bf16), gate weights prescaled ----------
    // bfr_g[g][0..3]: Whh2 k 0..127 ; bfr_g[g][4]: W_ih_m (panel k 128..159)
    s16x8 bfr_g[4][5], bfr_e[4];
    float bs_r[4];
    #pragma unroll
    for (int g = 0; g < 4; ++g) {
        const float sg = (g == 2) ? (2.0f * LOG2E) : LOG2E;
        const float* rh2 = whh2 + (g * HID + jh) * HID;
        const float* rih = W_ih + (g * HID + jh) * (2 * FEAT);
        #pragma unroll
        for (int s = 0; s < 4; ++s) {
            s16x8 fr;
            #pragma unroll
            for (int j = 0; j < 8; ++j)
                fr[j] = (short)to_bf16(rh2[32 * s + 8 * gidx + j] * sg);
            bfr_g[g][s] = fr;
        }
        {   // m-part: panel k 128..159 <-> f_m = 8*gidx+j (standard slots)
            s16x8 fr;
            #pragma unroll
            for (int j = 0; j < 8; ++j) {
                int fm = 8 * gidx + j;
                fr[j] = (short)to_bf16(fm < FEAT ? rih[FEAT + fm] * sg : 0.0f);
            }
            bfr_g[g][4] = fr;
        }
        {   // e-part: CUSTOM slot permutation f = j<4 ? 4g+j : 16+4g+(j-4)
            s16x8 fr;
            #pragma unroll
            for (int j = 0; j < 8; ++j) {
                int f = (j < 4) ? (4 * gidx + j) : (16 + 4 * gidx + (j - 4));
                fr[j] = (short)to_bf16(f < FEAT ? rih[f] * sg : 0.0f);
            }
            bfr_e[g] = fr;
        }
        float bb = b_ih[g * HID + jh] + b_hh[g * HID + jh];
        #pragma unroll
        for (int f = 0; f < FEAT; ++f) bb += rih[f] * b_reg[f];   // fold b_reg
        bs_r[g] = bb * sg;
    }
    s16x8 bfr_d;
    {
        const float* rw = W_decay + jh * FEAT;
        #pragma unroll
        for (int j = 0; j < 8; ++j) {
            int f = 8 * gidx + j;
            bfr_d[j] = (short)to_bf16(f < FEAT ? rw[f] * LOG2E : 0.0f);
        }
    }
    const float bd_r = b_decay[jh] * LOG2E;
    // swapped-xh A-frags: wregT[tile][s], A'[row=f=cidx(+16)][k=32s+8gidx+j]
    s16x8 wregT[2][4];
    #pragma unroll
    for (int s = 0; s < 4; ++s) {
        s16x8 fa, fb;
        #pragma unroll
        for (int j = 0; j < 8; ++j) {
            int k = 32 * s + 8 * gidx + j;
            fa[j] = (short)to_bf16(W_reg[cidx * HID + k]);
            fb[j] = (short)to_bf16((16 + cidx < FEAT) ? W_reg[(16 + cidx) * HID + k] : 0.0f);
        }
        wregT[0][s] = fa; wregT[1][s] = fb;
    }
    // xh bias in D'-layout: elem v <-> f = 4*gidx+v (tile1), 16+4*gidx+v (tile2)
    float brT1[4], brT2[4];
    #pragma unroll
    for (int v = 0; v < 4; ++v) {
        brT1[v] = b_reg[4 * gidx + v];
        int f2 = 16 + 4 * gidx + v;
        brT2[v] = (f2 < FEAT) ? b_reg[f2] : 0.0f;
    }
    __syncthreads();   // zero-init visible before prologue panel writes

    // ---------- prologue: staging on waves 2..7 ----------
    const int st  = tid - 128;
    const bool stg = (st >= 0) && (st < BT * FEAT);
    const int rr = stg ? st / FEAT : 0;
    const int ff = stg ? (st - rr * FEAT) : 0;
    const int rowbase = (bbase + rr) * (T_LEN * FEAT) + ff;
    float nx = 0.f, nm = 0.f, nd = 0.f;
    if (stg) {
        float x0 = values[rowbase], m0 = masks[rowbase];
        xm_s[0][rr][ff] = make_float2(x0, m0);
        ak_s[0][rr][128 + ff] = to_bf16(m0);            // m(0) -> panel[0]
        nx = values[rowbase + FEAT];
        nm = masks[rowbase + FEAT];
        nd = deltas[rowbase + FEAT];
    }
    const int ibase = (bbase + cidx) * (T_LEN * FEAT);   // imp store base (row=cidx)
    float c_r[4]   = {0.f, 0.f, 0.f, 0.f};
    float h_r[4]   = {0.f, 0.f, 0.f, 0.f};
    float gam_r[4] = {0.f, 0.f, 0.f, 0.f};   // h=0 at t=0 -> value irrelevant
    float xl_acc = 0.0f;
    __syncthreads();

    int bufw = 1;    // xm buffer written by P(t) = (t+1)%3
    int bufr = 0;    // xm buffer read by Q(t) = t%3
    for (int t = 0; t < T_LEN; ++t) {
        const int par = t & 1;

        // ---- P: flush t+1 stages, issue t+2 loads, h_d -> panel[par] ----
        float lx = 0.f, lm = 0.f, ld = 0.f;
        if (stg) {
            d_s[par ^ 1][rr][ff] = to_bf16f(nd);
            xm_s[bufw][rr][ff] = make_float2(nx, nm);
            int idx = (t + 2 < T_LEN) ? (t + 2) : (T_LEN - 1);
            int o = rowbase + idx * FEAT;
            lx = values[o]; lm = masks[o]; ld = deltas[o];
        }
        #pragma unroll
        for (int v = 0; v < 4; ++v)
            ak_s[par][4 * gidx + v][jh] = to_bf16f(h_r[v] * gam_r[v]);
        __syncthreads();                               // bar1 (the only barrier)

        // ---- Q: all LDS reads up front ----
        s16x8 aF0 = *(const s16x8*)&ak_s[par][cidx][      8 * gidx];
        s16x8 aF1 = *(const s16x8*)&ak_s[par][cidx][ 32 + 8 * gidx];
        s16x8 aF2 = *(const s16x8*)&ak_s[par][cidx][ 64 + 8 * gidx];
        s16x8 aF3 = *(const s16x8*)&ak_s[par][cidx][ 96 + 8 * gidx];
        s16x8 aM  = *(const s16x8*)&ak_s[par][cidx][128 + 8 * gidx];
        s16x8 ad  = *(const s16x8*)&d_s[par ^ 1][cidx][8 * gidx];
        float2 xm1[4], xm2[4];
        #pragma unroll
        for (int v = 0; v < 4; ++v) {
            xm1[v] = xm_s[bufr][cidx][4 * gidx + v];
            xm2[v] = xm_s[bufr][cidx][16 + 4 * gidx + v];   // zero-padded rows
        }
        if (stg) ak_s[par ^ 1][rr][128 + ff] = to_bf16f(nm);   // m(t+1)

        // swapped xh: xh^T = W_reg @ h_d^T  (A = wregT, B = aF as B-frag)
        f32x4 xaccT1 = {brT1[0], brT1[1], brT1[2], brT1[3]};
        f32x4 xaccT2 = {brT2[0], brT2[1], brT2[2], brT2[3]};
        xaccT1 = MFMA16(wregT[0][0], aF0, xaccT1); xaccT2 = MFMA16(wregT[1][0], aF0, xaccT2);
        xaccT1 = MFMA16(wregT[0][1], aF1, xaccT1); xaccT2 = MFMA16(wregT[1][1], aF1, xaccT2);
        xaccT1 = MFMA16(wregT[0][2], aF2, xaccT1); xaccT2 = MFMA16(wregT[1][2], aF2, xaccT2);
        xaccT1 = MFMA16(wregT[0][3], aF3, xaccT1); xaccT2 = MFMA16(wregT[1][3], aF3, xaccT2);

        // gate MFMAs (independent): fill the pipe while xh completes
        f32x4 acc0 = {bs_r[0], bs_r[0], bs_r[0], bs_r[0]};
        f32x4 acc1 = {bs_r[1], bs_r[1], bs_r[1], bs_r[1]};
        f32x4 acc2 = {bs_r[2], bs_r[2], bs_r[2], bs_r[2]};
        f32x4 acc3 = {bs_r[3], bs_r[3], bs_r[3], bs_r[3]};
        acc0 = MFMA16(aF0, bfr_g[0][0], acc0); acc1 = MFMA16(aF0, bfr_g[1][0], acc1);
        acc2 = MFMA16(aF0, bfr_g[2][0], acc2); acc3 = MFMA16(aF0, bfr_g[3][0], acc3);
        acc0 = MFMA16(aF1, bfr_g[0][1], acc0); acc1 = MFMA16(aF1, bfr_g[1][1], acc1);
        acc2 = MFMA16(aF1, bfr_g[2][1], acc2); acc3 = MFMA16(aF1, bfr_g[3][1], acc3);
        acc0 = MFMA16(aF2, bfr_g[0][2], acc0); acc1 = MFMA16(aF2, bfr_g[1][2], acc1);
        acc2 = MFMA16(aF2, bfr_g[2][2], acc2); acc3 = MFMA16(aF2, bfr_g[3][2], acc3);
        acc0 = MFMA16(aF3, bfr_g[0][3], acc0); acc1 = MFMA16(aF3, bfr_g[1][3], acc1);
        acc2 = MFMA16(aF3, bfr_g[2][3], acc2); acc3 = MFMA16(aF3, bfr_g[3][3], acc3);
        acc0 = MFMA16(aM, bfr_g[0][4], acc0);  acc1 = MFMA16(aM, bfr_g[1][4], acc1);
        acc2 = MFMA16(aM, bfr_g[2][4], acc2);  acc3 = MFMA16(aM, bfr_g[3][4], acc3);
        f32x4 gacc = {bd_r, bd_r, bd_r, bd_r};
        gacc = MFMA16(ad, bfr_d, gacc);

        // e in registers, packed into A-frag with the custom slot permutation
        float e1[4], e2[4];
        s16x8 eF;
        #pragma unroll
        for (int v = 0; v < 4; ++v) {
            e1[v] = xm1[v].y * (xm1[v].x - xaccT1[v]);
            e2[v] = xm2[v].y * (xm2[v].x - xaccT2[v]);
            eF[v]     = (short)to_bf16f(e1[v]);
            eF[4 + v] = (short)to_bf16f(e2[v]);
        }
        acc0 = MFMA16(eF, bfr_e[0], acc0);
        acc1 = MFMA16(eF, bfr_e[1], acc1);
        acc2 = MFMA16(eF, bfr_e[2], acc2);
        acc3 = MFMA16(eF, bfr_e[3], acc3);

        // off-path: imputation store + loss (m in {0,1} -> |e| = |x-xh|*m)
        const float rd = rden_s[t];
        if (wv == 0) {
            #pragma unroll
            for (int v = 0; v < 4; ++v) {
                out_imp[ibase + t * FEAT + 4 * gidx + v] = xaccT1[v] + e1[v];
                xl_acc += fabsf(e1[v]) * rd;
            }
        } else if (wv == 1) {
            #pragma unroll
            for (int v = 0; v < 4; ++v) {
                int f2 = 16 + 4 * gidx + v;
                if (f2 < FEAT) {
                    out_imp[ibase + t * FEAT + f2] = xaccT2[v] + e2[v];
                    xl_acc += fabsf(e2[v]) * rd;
                }
            }
        }

        if (stg) { nx = lx; nm = lm; nd = ld; }

        // ---- R: pointwise (all regs) ----
        #pragma unroll
        for (int v = 0; v < 4; ++v) {
            float ig = rcp_f(1.0f + exp2_f(-acc0[v]));
            float fg = rcp_f(1.0f + exp2_f(-acc1[v]));
            float gg = 2.0f * rcp_f(1.0f + exp2_f(-acc2[v])) - 1.0f;
            float og = rcp_f(1.0f + exp2_f(-acc3[v]));
            c_r[v] = fg * c_r[v] + ig * gg;
            float th = 2.0f * rcp_f(1.0f + exp2_f(-2.0f * LOG2E * c_r[v])) - 1.0f;
            h_r[v] = og * th;
            gam_r[v] = exp2_f(-fmaxf(gacc[v], 0.0f));
        }
        int nb = bufw + 1; bufw = (nb > 2) ? 0 : nb;
        int nr = bufr + 1; bufr = (nr > 2) ? 0 : nr;
    }

    // ---------- epilogue ----------
    #pragma unroll
    for (int v = 0; v < 4; ++v) hfin_s[4 * gidx + v][jh] = h_r[v];
    red_s[tid] = xl_acc;
    __syncthreads();
    #pragma unroll
    for (int s = NTHR / 2; s > 0; s >>= 1) {
        if (tid < s) red_s[tid] += red_s[tid + s];
        __syncthreads();
    }
    if (tid == 0) xlpart[blk] = red_s[0];

    float yerr = 0.0f, ytr = 0.0f;
    if (tid < BT) {
        float acc = b_out[0];
        for (int k = 0; k < HID; ++k) acc += W_out[k] * hfin_s[tid][k];
        out_yh[bbase + tid] = acc;
        float it = is_train[bbase + tid];
        float dv = acc - labels[bbase + tid];
        yerr = dv * dv * it;
        ytr  = it;
    }
    #pragma unroll
    for (int s = 8; s > 0; s >>= 1) {
        yerr += __shfl_down(yerr, s);
        ytr  += __shfl_down(ytr, s);
    }
    if (tid == 0) { wsynum[blk] = yerr; wsyden[blk] = ytr; }
}

__global__ __launch_bounds__(256) void rits_final(
    const float* __restrict__ xlpart,
    const float* __restrict__ wsynum, const float* __restrict__ wsyden,
    float* __restrict__ d_out)
{
    __shared__ float sx[256], sy[256], sz[256];
    int tid = threadIdx.x;
    sx[tid] = xlpart[tid];
    sy[tid] = wsynum[tid];
    sz[tid] = wsyden[tid];
    __syncthreads();
    for (int s = 128; s > 0; s >>= 1) {
        if (tid < s) { sx[tid] += sx[tid + s]; sy[tid] += sy[tid + s]; sz[tid] += sz[tid + s]; }
        __syncthreads();
    }
    if (tid == 0) d_out[0] = sx[0] + sy[0] / (sz[0] + 1e-5f);
}

extern "C" void kernel_launch(void* const* d_in, const int* in_sizes, int n_in,
                              void* d_out, int out_size, void* d_ws, size_t ws_size,
                              hipStream_t stream)
{
    const float* values    = (const float*)d_in[0];
    const float* masks     = (const float*)d_in[1];
    const float* deltas    = (const float*)d_in[2];
    // d_in[3] evals, d_in[4] eval_masks : unused
    const float* labels    = (const float*)d_in[5];
    const float* is_train  = (const float*)d_in[6];
    const float* W_decay   = (const float*)d_in[7];
    const float* b_decay   = (const float*)d_in[8];
    const float* W_reg     = (const float*)d_in[9];
    const float* b_reg     = (const float*)d_in[10];
    const float* W_ih      = (const float*)d_in[11];
    const float* W_hh      = (const float*)d_in[12];
    const float* b_ih      = (const float*)d_in[13];
    const float* b_hh      = (const float*)d_in[14];
    const float* W_out     = (const float*)d_in[15];
    const float* b_out     = (const float*)d_in[16];

    float* ws     = (float*)d_ws;
    float* whh2   = ws + WS_WHH2;
    float* rden   = ws + WS_RDEN;
    float* xlpart = ws + WS_XL;
    float* wsynum = ws + WS_YNUM;
    float* wsyden = ws + WS_YDEN;

    float* out     = (float*)d_out;
    float* out_yh  = out + 1;
    float* out_imp = out + 1 + BTOT;

    rits_den<<<dim3(T_LEN), dim3(1024), 0, stream>>>(masks, rden);
    rits_fold<<<dim3(256), dim3(256), 0, stream>>>(W_ih, W_hh, W_reg, whh2);

    rits_main<<<dim3(NB), dim3(NTHR), 0, stream>>>(
        values, masks, deltas, labels, is_train,
        W_decay, b_decay, W_reg, b_reg, W_ih, W_hh, b_ih, b_hh, W_out, b_out,
        whh2, rden, out_yh, out_imp, xlpart, wsynum, wsyden);

    rits_final<<<dim3(1), dim3(256), 0, stream>>>(xlpart, wsynum, wsyden, out);
}

// Round 9
// 401.574 us; speedup vs baseline: 1.2448x; 1.1277x over previous
//
#include <hip/hip_runtime.h>
#include <math.h>

// RITS recurrent model, MFMA bf16, 2-barrier step (r6 base) + consolidation:
//  - t-loop unrolled x2, ALL step buffers 2-way indexed by par=t&1 (compile-time
//    after unroll -> immediate LDS offsets, less addressing VALU)
//  - imp store + x-loss offloaded from waves 0/1 to staging lanes (next step),
//    via xc_s f32 scratch + e read from the e-panel -> bar2 skew shrinks
//  - accumulator chains split (accA: s0,s1,m | accB: s2,s3,e; xh 2+2)
// 256 blocks x 512 threads (8 waves), block owns 16 batch rows.
// Wave w owns jh cols [16w,16w+16). MFMA 16x16x32 lane layout (m89-verified):
//   cidx=l&15 (A row / D col), gidx=l>>4; D: row=4*gidx+v, col=cidx.
// Folding: Whh2 = W_hh + W_ih_x@W_reg, bias += W_ih_x@b_reg;
//   gates = Whh2@h_d + W_ih_m@m + W_ih_x@e + b,  e = m*(x - x_h), xc = xh + e.
// Panel ak_s[par][row][k]: k 0..127 h_d | 128..159 e | 160..191 m (pads zero).
// Per-step (par=t&1):
//   P: stg: d(t+1)->d_s[par^1], xm(t+1)->xm_s[par^1], issue loads t+2
//      all: h*gamma -> panel[par] h-section
//   bar1
//   Q: all: gate MFMAs (accA/accB) + gamma(t+1) MFMA
//      stg: m(t+1)->panel[par^1]; t>0: read xc_s[par^1] + e-panel[par^1],
//           store imp(t-1), xl_acc += |e|*rden[t-1]
//      wv<2: xh MFMAs (2+2) -> e -> panel[par] e-section; xc -> xc_s[par]
//   bar2
//   R: e-MFMAs (accB) + combine + pointwise (exp2/rcp, prescaled log2e)
// Race audit (write | bars | read | bars | rewrite), 2 buffers each:
//   h panel[par]: W P(t) |b1| R Q(t) |b2,b1| W P(t+2)            OK
//   e panel[par]: W Q(t) |b2,b1| R R(t)+Qstg(t+1) |b2,b1| W Q(t+2) OK
//   m panel[par^1]: W Q(t) |b2,b1| R Q(t+1) |b2,b1| W Q(t+2)     OK
//   d_s[par^1]: W P(t) |b1| R Q(t) |b2,b1| W P(t+2)              OK
//   xm_s[par^1]: W P(t) |b1,b2,b1| R Q(t+1) |b2| W P(t+2)        OK
//   xc_s[par]: W Q(t) |b2,b1| R Qstg(t+1) |b2,b1| W Q(t+2)       OK

#define T_LEN 252
#define FEAT  21
#define HID   128
#define BTOT  4096
#define BT    16
#define NB    (BTOT / BT)   // 256
#define NTHR  512
#define LOG2E 1.44269504088896f

// ws layout (floats)
#define WS_WHH2   0        // [512][128] folded recurrent weight
#define WS_RDEN   65536    // [256] (252 used)
#define WS_XL     65792    // [256]
#define WS_YNUM   66048    // [256]
#define WS_YDEN   66304    // [256]

typedef __attribute__((ext_vector_type(8))) short s16x8;
typedef __attribute__((ext_vector_type(4))) float f32x4;

#define MFMA16(A, B, C) __builtin_amdgcn_mfma_f32_16x16x32_bf16((A), (B), (C), 0, 0, 0)

__device__ __forceinline__ float exp2_f(float x) { return __builtin_amdgcn_exp2f(x); }
__device__ __forceinline__ float rcp_f(float x)  { return __builtin_amdgcn_rcpf(x); }
__device__ __forceinline__ unsigned short to_bf16(float x) {   // RNE (setup only)
    unsigned int u = __float_as_uint(x);
    return (unsigned short)((u + 0x7FFFu + ((u >> 16) & 1u)) >> 16);
}
__device__ __forceinline__ unsigned short to_bf16f(float x) {  // round-half-up, 2 ops
    return (unsigned short)((__float_as_uint(x) + 0x8000u) >> 16);
}
__device__ __forceinline__ float bf16_to_f(unsigned short u) {
    return __uint_as_float(((unsigned int)u) << 16);
}

// ---- pre-pass 1: rden[t] = 1 / (sum_{b,f} masks[b][t][f] + 1e-5) ----
__global__ __launch_bounds__(1024) void rits_den(
    const float* __restrict__ masks, float* __restrict__ rden)
{
    const int t = blockIdx.x;
    const int tid = threadIdx.x;
    __shared__ float red[1024];
    float acc = 0.0f;
    if (tid < 48 * FEAT) {
        int r0 = tid / FEAT, f = tid - r0 * FEAT;
        for (int r = r0; r < BTOT; r += 48)
            acc += masks[r * (T_LEN * FEAT) + t * FEAT + f];
    }
    red[tid] = acc;
    __syncthreads();
    #pragma unroll
    for (int s = 512; s > 0; s >>= 1) {
        if (tid < s) red[tid] += red[tid + s];
        __syncthreads();
    }
    if (tid == 0) rden[t] = 1.0f / (red[0] + 1e-5f);
}

// ---- pre-pass 2: Whh2 = W_hh + W_ih[:, :FEAT] @ W_reg  (fp32) ----
__global__ __launch_bounds__(256) void rits_fold(
    const float* __restrict__ W_ih, const float* __restrict__ W_hh,
    const float* __restrict__ W_reg, float* __restrict__ whh2)
{
    int idx = blockIdx.x * 256 + threadIdx.x;       // 0..65535
    int j4 = idx >> 7, k = idx & (HID - 1);
    float acc = W_hh[j4 * HID + k];
    #pragma unroll
    for (int f = 0; f < FEAT; ++f)
        acc += W_ih[j4 * (2 * FEAT) + f] * W_reg[f * HID + k];
    whh2[idx] = acc;
}

__global__ __launch_bounds__(NTHR, 2) void rits_main(
    const float* __restrict__ values, const float* __restrict__ masks,
    const float* __restrict__ deltas,
    const float* __restrict__ labels, const float* __restrict__ is_train,
    const float* __restrict__ W_decay, const float* __restrict__ b_decay,
    const float* __restrict__ W_reg, const float* __restrict__ b_reg,
    const float* __restrict__ W_ih, const float* __restrict__ W_hh,
    const float* __restrict__ b_ih, const float* __restrict__ b_hh,
    const float* __restrict__ W_out, const float* __restrict__ b_out,
    const float* __restrict__ whh2, const float* __restrict__ rden,
    float* __restrict__ out_yh,     // [BTOT]
    float* __restrict__ out_imp,    // [BTOT][T][FEAT]
    float* __restrict__ xlpart, float* __restrict__ wsynum, float* __restrict__ wsyden)
{
    const int tid  = threadIdx.x;
    const int blk  = blockIdx.x;
    const int bbase = blk * BT;
    const int l    = tid & 63;
    const int wv   = tid >> 6;          // wave 0..7
    const int cidx = l & 15;
    const int gidx = l >> 4;            // k-group 0..3
    const int jh   = 16 * wv + cidx;    // owned hidden column

    __shared__ unsigned short ak_s[2][BT][200];
    __shared__ unsigned short d_s[2][BT][40];     // bf16 deltas, cols 21..39 zero
    __shared__ float2 xm_s[2][BT][22];            // (x, m) fp32
    __shared__ float xc_s[2][BT][22];             // fp32 x_c handoff to stg lanes
    __shared__ float hfin_s[BT][HID + 4];
    __shared__ float rden_s[T_LEN];
    __shared__ float red_s[NTHR];

    for (int i = tid; i < 2 * BT * 200; i += NTHR) ((unsigned short*)ak_s)[i] = 0;
    for (int i = tid; i < 2 * BT * 40;  i += NTHR) ((unsigned short*)d_s)[i] = 0;
    if (tid < T_LEN) rden_s[tid] = rden[tid];

    // ---------- one-time B-fragments (bf16), gate weights prescaled ----------
    // bfr_g[g][0..3]: Whh2 k 0..127 ; [4]: W_ih_x (e, k 128..159) ; [5]: W_ih_m (m, k 160..191)
    s16x8 bfr_g[4][6];
    float bs_r[4];
    #pragma unroll
    for (int g = 0; g < 4; ++g) {
        const float sg = (g == 2) ? (2.0f * LOG2E) : LOG2E;
        const float* rh2 = whh2 + (g * HID + jh) * HID;
        const float* rih = W_ih + (g * HID + jh) * (2 * FEAT);
        #pragma unroll
        for (int s = 0; s < 4; ++s) {
            s16x8 fr;
            #pragma unroll
            for (int j = 0; j < 8; ++j)
                fr[j] = (short)to_bf16(rh2[32 * s + 8 * gidx + j] * sg);
            bfr_g[g][s] = fr;
        }
        {   // e-part: k 128..159 <-> f = 8*gidx+j
            s16x8 fr;
            #pragma unroll
            for (int j = 0; j < 8; ++j) {
                int f = 8 * gidx + j;
                fr[j] = (short)to_bf16(f < FEAT ? rih[f] * sg : 0.0f);
            }
            bfr_g[g][4] = fr;
        }
        {   // m-part: k 160..191 <-> f = 8*gidx+j
            s16x8 fr;
            #pragma unroll
            for (int j = 0; j < 8; ++j) {
                int fm = 8 * gidx + j;
                fr[j] = (short)to_bf16(fm < FEAT ? rih[FEAT + fm] * sg : 0.0f);
            }
            bfr_g[g][5] = fr;
        }
        float bb = b_ih[g * HID + jh] + b_hh[g * HID + jh];
        #pragma unroll
        for (int f = 0; f < FEAT; ++f) bb += rih[f] * b_reg[f];   // fold b_reg
        bs_r[g] = bb * sg;
    }
    s16x8 bfr_d;
    {
        const float* rw = W_decay + jh * FEAT;
        #pragma unroll
        for (int j = 0; j < 8; ++j) {
            int f = 8 * gidx + j;
            bfr_d[j] = (short)to_bf16(f < FEAT ? rw[f] * LOG2E : 0.0f);
        }
    }
    const float bd_r = b_decay[jh] * LOG2E;
    // x_h weights (waves 0,1 own output col f = 16wv+cidx), NOT prescaled
    const int  fx  = 16 * wv + cidx;
    const bool fxv = (wv < 2) && (fx < FEAT);
    const int  fxc = fxv ? fx : 0;
    s16x8 bfr_r[4];
    #pragma unroll
    for (int s = 0; s < 4; ++s) {
        s16x8 fr;
        #pragma unroll
        for (int j = 0; j < 8; ++j) {
            int k = 32 * s + 8 * gidx + j;
            fr[j] = (short)to_bf16(fxv ? W_reg[fxc * HID + k] : 0.0f);
        }
        bfr_r[s] = fr;
    }
    const float br_r = fxv ? b_reg[fxc] : 0.0f;
    __syncthreads();   // zero-init visible before prologue panel writes

    // ---------- prologue: staging on waves 2..7 ----------
    const int st  = tid - 128;
    const bool stg = (st >= 0) && (st < BT * FEAT);
    const int rr = stg ? st / FEAT : 0;
    const int ff = stg ? (st - rr * FEAT) : 0;
    const int rowbase = (bbase + rr) * (T_LEN * FEAT) + ff;
    float nx = 0.f, nm = 0.f, nd = 0.f;
    if (stg) {
        float x0 = values[rowbase], m0 = masks[rowbase];
        xm_s[0][rr][ff] = make_float2(x0, m0);
        ak_s[0][rr][160 + ff] = to_bf16(m0);            // m(0) -> panel[0]
        nx = values[rowbase + FEAT];
        nm = masks[rowbase + FEAT];
        nd = deltas[rowbase + FEAT];
    }
    float c_r[4]   = {0.f, 0.f, 0.f, 0.f};
    float h_r[4]   = {0.f, 0.f, 0.f, 0.f};
    float gam_r[4] = {0.f, 0.f, 0.f, 0.f};   // h=0 at t=0 -> value irrelevant
    float xl_acc = 0.0f;
    __syncthreads();

    #pragma unroll 2
    for (int t = 0; t < T_LEN; ++t) {
        const int par = t & 1;

        // ---- P: flush t+1 stages, issue t+2 loads, h_d -> panel[par] ----
        float lx = 0.f, lm = 0.f, ld = 0.f;
        if (stg) {
            d_s[par ^ 1][rr][ff] = to_bf16f(nd);
            xm_s[par ^ 1][rr][ff] = make_float2(nx, nm);
            int idx = (t + 2 < T_LEN) ? (t + 2) : (T_LEN - 1);
            int o = rowbase + idx * FEAT;
            lx = values[o]; lm = masks[o]; ld = deltas[o];
        }
        #pragma unroll
        for (int v = 0; v < 4; ++v)
            ak_s[par][4 * gidx + v][jh] = to_bf16f(h_r[v] * gam_r[v]);
        __syncthreads();                                // bar1

        // ---- Q ----
        s16x8 aF0 = *(const s16x8*)&ak_s[par][cidx][      8 * gidx];
        s16x8 aF1 = *(const s16x8*)&ak_s[par][cidx][ 32 + 8 * gidx];
        s16x8 aF2 = *(const s16x8*)&ak_s[par][cidx][ 64 + 8 * gidx];
        s16x8 aF3 = *(const s16x8*)&ak_s[par][cidx][ 96 + 8 * gidx];
        s16x8 aM  = *(const s16x8*)&ak_s[par][cidx][160 + 8 * gidx];
        s16x8 ad  = *(const s16x8*)&d_s[par ^ 1][cidx][8 * gidx];
        if (stg) {
            ak_s[par ^ 1][rr][160 + ff] = to_bf16f(nm);   // m(t+1)
            if (t > 0) {   // offloaded imp store + loss for step t-1
                float xcp = xc_s[par ^ 1][rr][ff];
                float ep  = bf16_to_f(ak_s[par ^ 1][rr][128 + ff]);
                out_imp[rowbase + (t - 1) * FEAT] = xcp;
                xl_acc += fabsf(ep) * rden_s[t - 1];
            }
        }

        // gate MFMAs, split chains: accA = b + s0,s1,m ; accB = s2,s3 (+e in R)
        f32x4 accA0 = {bs_r[0], bs_r[0], bs_r[0], bs_r[0]};
        f32x4 accA1 = {bs_r[1], bs_r[1], bs_r[1], bs_r[1]};
        f32x4 accA2 = {bs_r[2], bs_r[2], bs_r[2], bs_r[2]};
        f32x4 accA3 = {bs_r[3], bs_r[3], bs_r[3], bs_r[3]};
        f32x4 accB0 = {0.f, 0.f, 0.f, 0.f};
        f32x4 accB1 = {0.f, 0.f, 0.f, 0.f};
        f32x4 accB2 = {0.f, 0.f, 0.f, 0.f};
        f32x4 accB3 = {0.f, 0.f, 0.f, 0.f};
        accA0 = MFMA16(aF0, bfr_g[0][0], accA0); accA1 = MFMA16(aF0, bfr_g[1][0], accA1);
        accA2 = MFMA16(aF0, bfr_g[2][0], accA2); accA3 = MFMA16(aF0, bfr_g[3][0], accA3);
        accB0 = MFMA16(aF2, bfr_g[0][2], accB0); accB1 = MFMA16(aF2, bfr_g[1][2], accB1);
        accB2 = MFMA16(aF2, bfr_g[2][2], accB2); accB3 = MFMA16(aF2, bfr_g[3][2], accB3);
        accA0 = MFMA16(aF1, bfr_g[0][1], accA0); accA1 = MFMA16(aF1, bfr_g[1][1], accA1);
        accA2 = MFMA16(aF1, bfr_g[2][1], accA2); accA3 = MFMA16(aF1, bfr_g[3][1], accA3);
        accB0 = MFMA16(aF3, bfr_g[0][3], accB0); accB1 = MFMA16(aF3, bfr_g[1][3], accB1);
        accB2 = MFMA16(aF3, bfr_g[2][3], accB2); accB3 = MFMA16(aF3, bfr_g[3][3], accB3);
        accA0 = MFMA16(aM, bfr_g[0][5], accA0);  accA1 = MFMA16(aM, bfr_g[1][5], accA1);
        accA2 = MFMA16(aM, bfr_g[2][5], accA2);  accA3 = MFMA16(aM, bfr_g[3][5], accA3);
        f32x4 gacc = {bd_r, bd_r, bd_r, bd_r};
        gacc = MFMA16(ad, bfr_d, gacc);

        if (wv < 2) {
            // xh split 2+2
            f32x4 x1 = {br_r, br_r, br_r, br_r};
            f32x4 x2 = {0.f, 0.f, 0.f, 0.f};
            x1 = MFMA16(aF0, bfr_r[0], x1);
            x2 = MFMA16(aF2, bfr_r[2], x2);
            x1 = MFMA16(aF1, bfr_r[1], x1);
            x2 = MFMA16(aF3, bfr_r[3], x2);
            if (fxv) {
                #pragma unroll
                for (int v = 0; v < 4; ++v) {
                    float xh = x1[v] + x2[v];
                    float2 xm = xm_s[par][4 * gidx + v][fxc];
                    float e  = xm.y * (xm.x - xh);
                    ak_s[par][4 * gidx + v][128 + fxc] = to_bf16f(e);
                    xc_s[par][4 * gidx + v][fxc] = xh + e;
                }
            }
        }
        if (stg) { nx = lx; nm = lm; nd = ld; }
        __syncthreads();                                // bar2

        // ---- R: e-MFMAs (accB) + combine + pointwise ----
        s16x8 aE = *(const s16x8*)&ak_s[par][cidx][128 + 8 * gidx];
        accB0 = MFMA16(aE, bfr_g[0][4], accB0);
        accB1 = MFMA16(aE, bfr_g[1][4], accB1);
        accB2 = MFMA16(aE, bfr_g[2][4], accB2);
        accB3 = MFMA16(aE, bfr_g[3][4], accB3);
        #pragma unroll
        for (int v = 0; v < 4; ++v) {
            float g0 = accA0[v] + accB0[v];
            float g1 = accA1[v] + accB1[v];
            float g2 = accA2[v] + accB2[v];
            float g3 = accA3[v] + accB3[v];
            float ig = rcp_f(1.0f + exp2_f(-g0));
            float fg = rcp_f(1.0f + exp2_f(-g1));
            float gg = 2.0f * rcp_f(1.0f + exp2_f(-g2)) - 1.0f;
            float og = rcp_f(1.0f + exp2_f(-g3));
            c_r[v] = fg * c_r[v] + ig * gg;
            float th = 2.0f * rcp_f(1.0f + exp2_f(-2.0f * LOG2E * c_r[v])) - 1.0f;
            h_r[v] = og * th;
            gam_r[v] = exp2_f(-fmaxf(gacc[v], 0.0f));
        }
        // no barrier: P(t+1) writes are barrier-separated per audit
    }

    // ---------- final imp flush for t = T_LEN-1 (par = 1) ----------
    if (stg) {
        float xcp = xc_s[1][rr][ff];
        float ep  = bf16_to_f(ak_s[1][rr][128 + ff]);
        out_imp[rowbase + (T_LEN - 1) * FEAT] = xcp;
        xl_acc += fabsf(ep) * rden_s[T_LEN - 1];
    }

    // ---------- epilogue ----------
    #pragma unroll
    for (int v = 0; v < 4; ++v) hfin_s[4 * gidx + v][jh] = h_r[v];
    red_s[tid] = xl_acc;
    __syncthreads();
    #pragma unroll
    for (int s = NTHR / 2; s > 0; s >>= 1) {
        if (tid < s) red_s[tid] += red_s[tid + s];
        __syncthreads();
    }
    if (tid == 0) xlpart[blk] = red_s[0];

    float yerr = 0.0f, ytr = 0.0f;
    if (tid < BT) {
        float acc = b_out[0];
        for (int k = 0; k < HID; ++k) acc += W_out[k] * hfin_s[tid][k];
        out_yh[bbase + tid] = acc;
        float it = is_train[bbase + tid];
        float dv = acc - labels[bbase + tid];
        yerr = dv * dv * it;
        ytr  = it;
    }
    #pragma unroll
    for (int s = 8; s > 0; s >>= 1) {
        yerr += __shfl_down(yerr, s);
        ytr  += __shfl_down(ytr, s);
    }
    if (tid == 0) { wsynum[blk] = yerr; wsyden[blk] = ytr; }
}

__global__ __launch_bounds__(256) void rits_final(
    const float* __restrict__ xlpart,
    const float* __restrict__ wsynum, const float* __restrict__ wsyden,
    float* __restrict__ d_out)
{
    __shared__ float sx[256], sy[256], sz[256];
    int tid = threadIdx.x;
    sx[tid] = xlpart[tid];
    sy[tid] = wsynum[tid];
    sz[tid] = wsyden[tid];
    __syncthreads();
    for (int s = 128; s > 0; s >>= 1) {
        if (tid < s) { sx[tid] += sx[tid + s]; sy[tid] += sy[tid + s]; sz[tid] += sz[tid + s]; }
        __syncthreads();
    }
    if (tid == 0) d_out[0] = sx[0] + sy[0] / (sz[0] + 1e-5f);
}

extern "C" void kernel_launch(void* const* d_in, const int* in_sizes, int n_in,
                              void* d_out, int out_size, void* d_ws, size_t ws_size,
                              hipStream_t stream)
{
    const float* values    = (const float*)d_in[0];
    const float* masks     = (const float*)d_in[1];
    const float* deltas    = (const float*)d_in[2];
    // d_in[3] evals, d_in[4] eval_masks : unused
    const float* labels    = (const float*)d_in[5];
    const float* is_train  = (const float*)d_in[6];
    const float* W_decay   = (const float*)d_in[7];
    const float* b_decay   = (const float*)d_in[8];
    const float* W_reg     = (const float*)d_in[9];
    const float* b_reg     = (const float*)d_in[10];
    const float* W_ih      = (const float*)d_in[11];
    const float* W_hh      = (const float*)d_in[12];
    const float* b_ih      = (const float*)d_in[13];
    const float* b_hh      = (const float*)d_in[14];
    const float* W_out     = (const float*)d_in[15];
    const float* b_out     = (const float*)d_in[16];

    float* ws     = (float*)d_ws;
    float* whh2   = ws + WS_WHH2;
    float* rden   = ws + WS_RDEN;
    float* xlpart = ws + WS_XL;
    float* wsynum = ws + WS_YNUM;
    float* wsyden = ws + WS_YDEN;

    float* out     = (float*)d_out;
    float* out_yh  = out + 1;
    float* out_imp = out + 1 + BTOT;

    rits_den<<<dim3(T_LEN), dim3(1024), 0, stream>>>(masks, rden);
    rits_fold<<<dim3(256), dim3(256), 0, stream>>>(W_ih, W_hh, W_reg, whh2);

    rits_main<<<dim3(NB), dim3(NTHR), 0, stream>>>(
        values, masks, deltas, labels, is_train,
        W_decay, b_decay, W_reg, b_reg, W_ih, W_hh, b_ih, b_hh, W_out, b_out,
        whh2, rden, out_yh, out_imp, xlpart, wsynum, wsyden);

    rits_final<<<dim3(1), dim3(256), 0, stream>>>(xlpart, wsynum, wsyden, out);
}